// Round 1
// baseline (5039.350 us; speedup 1.0000x reference)
//
#include <hip/hip_runtime.h>
#include <math.h>

// Problem constants (match reference)
#define BATCH  1024
#define SEQ    256
#define UNITS  256
#define NC     128
#define FOURU  1024   // 4*UNITS

// Step-kernel tiling
#define MB 32                 // batch rows per block
#define UB 16                 // units per block (x4 gates = 64 R-columns)
#define KC 64                 // K chunk staged in LDS
#define PADF 4                // pad floats -> row stride 68*4=272B, 16B-aligned
#define LSTR (KC + PADF)      // 68

// ---------------------------------------------------------------------------
// Zero a float region (ws is poisoned 0xAA before every timed call)
__global__ __launch_bounds__(256) void zero_ws(float* __restrict__ p, int n4) {
    int i = blockIdx.x * blockDim.x + threadIdx.x;
    if (i < n4) {
        float4 z = make_float4(0.f, 0.f, 0.f, 0.f);
        ((float4*)p)[i] = z;
    }
}

// ---------------------------------------------------------------------------
// One LSTM timestep:
//   z[b, u + 256g] = (h_in @ R)[b, u+256g] + kernel[inp[b][t]][u+256g] + bias[u+256g]
//   i,f,g,o gates -> c update -> h_out
// Grid: (BATCH/MB=32, UNITS/UB=16), block 256 threads.
// Thread (tx=tid&15 -> unit, ty=tid>>4 -> batch) owns b={ty, ty+16}, 1 unit, 4 gates.
__global__ __launch_bounds__(256) void lstm_step(
    const float* __restrict__ h_in,   // [1024][256]
    float*       __restrict__ h_out,  // [1024][256]
    float*       __restrict__ c_buf,  // [1024][256]
    const float* __restrict__ R,      // [256][1024] recurrent_kernel
    const float* __restrict__ Wk,     // [128][1024] kernel (one-hot gather)
    const float* __restrict__ bias,   // [1024]
    const int*   __restrict__ inp,    // [1024][256]
    int t)
{
    __shared__ float hs[MB][LSTR];        // 32 x 68 floats
    __shared__ float rs[4 * UB][LSTR];    // 64 x 68 floats (R^T chunk: [col][k])

    const int tid = threadIdx.x;
    const int tx  = tid & 15;     // unit within block
    const int ty  = tid >> 4;     // 0..15
    const int bt  = blockIdx.x;   // batch tile
    const int ut  = blockIdx.y;   // unit tile

    const int b0 = bt * MB;
    const int u0 = ut * UB;

    float acc[2][4];
#pragma unroll
    for (int i = 0; i < 2; i++)
#pragma unroll
        for (int g = 0; g < 4; g++) acc[i][g] = 0.f;

    for (int k0 = 0; k0 < UNITS; k0 += KC) {
        // --- stage h tile: 32 rows x 64 k = 512 float4, 2 per thread ---
#pragma unroll
        for (int i = 0; i < 2; i++) {
            int idx = tid + i * 256;          // 0..511
            int bb  = idx >> 4;               // 0..31
            int k4  = idx & 15;               // 0..15
            float4 v = *(const float4*)&h_in[(b0 + bb) * UNITS + k0 + k4 * 4];
            *(float4*)&hs[bb][k4 * 4] = v;
        }
        // --- stage R chunk transposed: cols = u0 + (q*4+j) + 256*g ---
#pragma unroll
        for (int i = 0; i < 4; i++) {
            int f  = tid + i * 256;           // 0..1023
            int kk = f >> 4;                  // 0..63
            int cq = f & 15;
            int g  = cq >> 2;
            int q  = cq & 3;
            float4 v = *(const float4*)&R[(k0 + kk) * FOURU + u0 + g * UNITS + q * 4];
            rs[g * UB + q * 4 + 0][kk] = v.x;
            rs[g * UB + q * 4 + 1][kk] = v.y;
            rs[g * UB + q * 4 + 2][kk] = v.z;
            rs[g * UB + q * 4 + 3][kk] = v.w;
        }
        __syncthreads();

        // --- FMA inner loop: per k4-group, 6 b128 LDS reads + 32 FMAs ---
#pragma unroll
        for (int k4 = 0; k4 < KC / 4; k4++) {
            float4 ha = *(const float4*)&hs[ty][k4 * 4];
            float4 hb = *(const float4*)&hs[ty + 16][k4 * 4];
#pragma unroll
            for (int g = 0; g < 4; g++) {
                float4 rv = *(const float4*)&rs[g * UB + tx][k4 * 4];
                acc[0][g] += ha.x * rv.x; acc[0][g] += ha.y * rv.y;
                acc[0][g] += ha.z * rv.z; acc[0][g] += ha.w * rv.w;
                acc[1][g] += hb.x * rv.x; acc[1][g] += hb.y * rv.y;
                acc[1][g] += hb.z * rv.z; acc[1][g] += hb.w * rv.w;
            }
        }
        __syncthreads();
    }

    // --- epilogue: gather + bias + gates + state update ---
    const int ug = u0 + tx;
#pragma unroll
    for (int i = 0; i < 2; i++) {
        int bg = b0 + ty + i * 16;
        int ch = inp[bg * SEQ + t];
        float z[4];
#pragma unroll
        for (int g = 0; g < 4; g++) {
            int col = ug + g * UNITS;
            z[g] = acc[i][g] + Wk[ch * FOURU + col] + bias[col];
        }
        float ig = 1.f / (1.f + expf(-z[0]));
        float fg = 1.f / (1.f + expf(-z[1]));
        float gg = tanhf(z[2]);
        float og = 1.f / (1.f + expf(-z[3]));
        int sidx = bg * UNITS + ug;
        float c_old = c_buf[sidx];
        float c_new = fg * c_old + ig * gg;
        c_buf[sidx] = c_new;
        h_out[sidx] = og * tanhf(c_new);
    }
}

// ---------------------------------------------------------------------------
// logits = h_last @ dense_w + dense_b ; softmax over 128 chars.
// One block (128 threads) per batch row.
__global__ __launch_bounds__(128) void dense_softmax(
    const float* __restrict__ h,   // [1024][256]
    const float* __restrict__ W,   // [256][128]
    const float* __restrict__ b,   // [128]
    float*       __restrict__ out) // [1024][128]
{
    __shared__ float hsr[UNITS];
    __shared__ float red[NC];
    const int bq = blockIdx.x;
    const int n  = threadIdx.x;

    hsr[n]       = h[bq * UNITS + n];
    hsr[n + 128] = h[bq * UNITS + n + 128];
    __syncthreads();

    float acc = b[n];
#pragma unroll 8
    for (int k = 0; k < UNITS; k++) acc += hsr[k] * W[k * NC + n];

    // max-reduce
    red[n] = acc;
    __syncthreads();
    for (int s = 64; s > 0; s >>= 1) {
        if (n < s) red[n] = fmaxf(red[n], red[n + s]);
        __syncthreads();
    }
    float m = red[0];
    __syncthreads();

    float e = expf(acc - m);
    red[n] = e;
    __syncthreads();
    for (int s = 64; s > 0; s >>= 1) {
        if (n < s) red[n] = red[n] + red[n + s];
        __syncthreads();
    }
    out[bq * NC + n] = e / red[0];
}

// ---------------------------------------------------------------------------
extern "C" void kernel_launch(void* const* d_in, const int* in_sizes, int n_in,
                              void* d_out, int out_size, void* d_ws, size_t ws_size,
                              hipStream_t stream)
{
    const int*   inp  = (const int*)d_in[0];    // [1024][256] int32
    const float* Wk   = (const float*)d_in[1];  // [128][1024]
    const float* R    = (const float*)d_in[2];  // [256][1024]
    const float* bias = (const float*)d_in[3];  // [1024]
    const float* Wd   = (const float*)d_in[4];  // [256][128]
    const float* bd   = (const float*)d_in[5];  // [128]
    float* out = (float*)d_out;

    // workspace layout: hA | hB | c  (each 1024*256 floats = 1 MB)
    float* hA = (float*)d_ws;
    float* hB = hA + BATCH * UNITS;
    float* cB = hB + BATCH * UNITS;

    // zero hA..c in one pass (hB is fully written by t=0 before being read)
    {
        int n4 = (3 * BATCH * UNITS) / 4;
        zero_ws<<<dim3((n4 + 255) / 256), dim3(256), 0, stream>>>(hA, n4);
    }

    dim3 grid(BATCH / MB, UNITS / UB);   // 32 x 16 = 512 blocks
    for (int t = 0; t < SEQ; t++) {
        const float* hin  = (t & 1) ? hB : hA;
        float*       hout = (t & 1) ? hA : hB;
        lstm_step<<<grid, dim3(256), 0, stream>>>(hin, hout, cB, R, Wk, bias, inp, t);
    }
    // t=255 is odd -> wrote hA
    dense_softmax<<<dim3(BATCH), dim3(128), 0, stream>>>(hA, Wd, bd, out);
}